// Round 5
// baseline (592.435 us; speedup 1.0000x reference)
//
#include <hip/hip_runtime.h>
#include <hip/hip_bf16.h>
#include <climits>
#include <math.h>

#define NN 200000
#define NE 600000
#define FD 128

// ws int layout (round-2 proven)
#define WS_CNT 0
#define WS_MIN1 16
#define WS_MIN2 (16 + NN)
#define WS_ACT  (16 + 2 * NN)
#define WS_PACK_BYTES ((size_t)(16 + 3 * NN) * 4)
#define W1P_ELEMS (48 * 256 * 8)
#define W2P_ELEMS (32 * 128 * 8)

typedef __attribute__((ext_vector_type(8))) short short8;
typedef __attribute__((ext_vector_type(4))) float f32x4;

__device__ __forceinline__ unsigned short f2bf(float f) {
    __hip_bfloat16 h = __float2bfloat16(f);
    return *reinterpret_cast<unsigned short*>(&h);
}

__device__ __forceinline__ void gl_lds16(const void* gp, void* lp) {
    __builtin_amdgcn_global_load_lds(
        (const __attribute__((address_space(1))) void*)gp,
        (__attribute__((address_space(3))) void*)lp, 16, 0, 0);
}

// Fused init + weight pack: disjoint ws regions, no mutual data deps.
__global__ __launch_bounds__(256) void k_init_pack(const float* __restrict__ w1,
                                                   const float* __restrict__ w2,
                                                   const float* __restrict__ mw1,
                                                   unsigned short* __restrict__ w1p,
                                                   unsigned short* __restrict__ w2p,
                                                   unsigned short* __restrict__ mw1p,
                                                   int* __restrict__ ws) {
    int i = blockIdx.x * 256 + threadIdx.x;
    if (i == 0) ws[WS_CNT] = 0;
    if (i < NN) { ws[WS_MIN1 + i] = INT_MAX; ws[WS_MIN2 + i] = INT_MAX; }
    // pack (round-2 proven layout): [kc][n][8] with value w[kc*8+j][n]
    if (i < 12288) {                      // w1: 48 kc x 256 n
        int kc = i >> 8, n = i & 255;
        #pragma unroll
        for (int j = 0; j < 8; ++j) w1p[i * 8 + j] = f2bf(w1[(kc * 8 + j) * 256 + n]);
    } else if (i < 12288 + 4096) {        // w2: 32 kc x 128 n
        int ii = i - 12288;
        int kc = ii >> 7, n = ii & 127;
        #pragma unroll
        for (int j = 0; j < 8; ++j) w2p[ii * 8 + j] = f2bf(w2[(kc * 8 + j) * 128 + n]);
    } else if (i < 12288 + 4096 + 1024) { // mw1: 16 kc x 64 n
        int ii = i - 16384;
        int kc = ii >> 6, n = ii & 63;
        #pragma unroll
        for (int j = 0; j < 8; ++j) mw1p[ii * 8 + j] = f2bf(mw1[(kc * 8 + j) * 64 + n]);
    }
}

// Two-pass min over symmetrized edges — exact round-2 data path (ungated).
__global__ __launch_bounds__(256) void k_min1(const int* __restrict__ ei, int* __restrict__ ws) {
    int e = blockIdx.x * 256 + threadIdx.x;
    if (e >= NE) return;
    int s = ei[e], d = ei[NE + e];
    if (s != d) {
        atomicMin(&ws[WS_MIN1 + s], d);
        atomicMin(&ws[WS_MIN1 + d], s);
    }
}

__global__ __launch_bounds__(256) void k_min2(const int* __restrict__ ei, int* __restrict__ ws) {
    int e = blockIdx.x * 256 + threadIdx.x;
    if (e >= NE) return;
    int s = ei[e], d = ei[NE + e];
    if (s != d) {
        if (d != ws[WS_MIN1 + s]) atomicMin(&ws[WS_MIN2 + s], d);
        if (s != ws[WS_MIN1 + d]) atomicMin(&ws[WS_MIN2 + d], s);
    }
}

// Fused: unconditional copy x->updated (round-2 proven; k_mlp later overwrites
// active rows) + compact/murray-default for this block's 8 rows (same code as
// round-2 k_compact, relocated; runs before k_mlp, after k_min2).
__global__ __launch_bounds__(256) void k_copy_compact(const float4* __restrict__ x,
                                                      float4* __restrict__ out,
                                                      const int* __restrict__ types,
                                                      int* __restrict__ ws) {
    int i = blockIdx.x * 256 + threadIdx.x;  // 25000 blocks * 256 = NN*FD/4
    out[i] = x[i];
    int t = threadIdx.x;
    if (t < 8) {
        int n = blockIdx.x * 8 + t;          // 25000*8 = NN exactly
        bool has_two = ws[WS_MIN2 + n] < NN; // min2 real => min1 real too
        bool is_bif = (types[n] == 1);
        out[(size_t)NN * FD / 4 + 0] = out[(size_t)NN * FD / 4 + 0];  // no-op removed below
    }
    // murray default + compact append (one thread per row)
    if (t < 8) {
        int n = blockIdx.x * 8 + t;
        bool has_two = ws[WS_MIN2 + n] < NN;
        bool is_bif = (types[n] == 1);
        ((float*)out)[(size_t)NN * FD + n] = is_bif ? 0.5f : 0.0f;
        if (is_bif && has_two) {
            int pos = atomicAdd(&ws[WS_CNT], 1);
            ws[WS_ACT + pos] = n;
        }
    }
}

// ---- MFMA MLP: 64 active nodes / block, 256 threads (4 waves) ---- (round-2 proven, verbatim)
#define REGA_BYTES 50432
#define PF_BYTE 34048
__global__ __launch_bounds__(256, 2) void k_mlp(
    const float* __restrict__ x,
    const float* __restrict__ b1, const float* __restrict__ b2,
    const float* __restrict__ ln_g, const float* __restrict__ ln_b,
    const float* __restrict__ mb1, const float* __restrict__ mw2, const float* __restrict__ mb2,
    const unsigned short* __restrict__ w1p, const unsigned short* __restrict__ w2p,
    const unsigned short* __restrict__ mw1p,
    const int* __restrict__ ws, float* __restrict__ out)
{
    __shared__ __align__(16) char smem[REGA_BYTES + 16384];
    __shared__ int nodes3[192];
    __shared__ float red[256];

    unsigned short* s_a16 = (unsigned short*)smem;
    short8* s_a8 = (short8*)smem;
    float* s_cF = (float*)smem;
    char* s_b = smem + REGA_BYTES;
    short8* s_b8 = (short8*)s_b;

    const int t = threadIdx.x;
    const int wv = t >> 6;
    const int lane = t & 63;
    const int q = lane >> 4;
    const int l16 = lane & 15;

    const int count = ws[WS_CNT];
    const int base = blockIdx.x * 64;
    if (base >= count) return;
    const int nvalid = min(64, count - base);

    if (t < 64) {
        int idx = min(base + t, count - 1);
        int node = ws[WS_ACT + idx];
        nodes3[t] = node;
        nodes3[64 + t] = ws[WS_MIN1 + node];
        nodes3[128 + t] = ws[WS_MIN2 + node];
    }
    __syncthreads();

    // Stage ctx as bf16 A-fragments: [kc=seg*16+(c>>3)][m][8]
    for (int i = t; i < 64 * 96; i += 256) {
        int m = i / 96;
        int f4 = i - m * 96;
        int seg = f4 >> 5;
        int c = (f4 & 31) * 4;
        int src = nodes3[seg * 64 + m];
        const float4 v = *(const float4*)&x[(size_t)src * FD + c];
        int k = seg * FD + c;
        int kc = k >> 3, j0 = k & 7;
        ushort4 p;
        p.x = f2bf(v.x); p.y = f2bf(v.y); p.z = f2bf(v.z); p.w = f2bf(v.w);
        *(ushort4*)&s_a16[(kc * 64 + m) * 8 + j0] = p;
    }

    // ---- GEMM1: C[64][256] = ctx[64][384] @ w1 ; wave wv owns n in [wv*64, wv*64+64) ----
    const int wn = wv * 64;
    f32x4 acc[4][4];
    #pragma unroll
    for (int a = 0; a < 4; ++a)
        #pragma unroll
        for (int b = 0; b < 4; ++b) acc[a][b] = (f32x4){0.f, 0.f, 0.f, 0.f};

    for (int p = 0; p < 12; ++p) {
        __syncthreads();
        {
            const char* src = (const char*)(w1p) + p * 16384;
            #pragma unroll
            for (int it = 0; it < 4; ++it) {
                int chunk = it * 4 + wv;
                gl_lds16(src + chunk * 1024 + lane * 16, s_b + chunk * 1024);
            }
        }
        __syncthreads();
        short8 a[4], b[4];
        #pragma unroll
        for (int mt = 0; mt < 4; ++mt) a[mt] = s_a8[(p * 4 + q) * 64 + mt * 16 + l16];
        #pragma unroll
        for (int nt = 0; nt < 4; ++nt) b[nt] = s_b8[q * 256 + wn + nt * 16 + l16];
        #pragma unroll
        for (int mt = 0; mt < 4; ++mt)
            #pragma unroll
            for (int nt = 0; nt < 4; ++nt)
                acc[mt][nt] = __builtin_amdgcn_mfma_f32_16x16x32_bf16(a[mt], b[nt], acc[mt][nt], 0, 0, 0);
    }
    __syncthreads();

    {
        float b1v[4];
        #pragma unroll
        for (int nt = 0; nt < 4; ++nt) b1v[nt] = b1[wn + nt * 16 + l16];
        #pragma unroll
        for (int mt = 0; mt < 4; ++mt)
            #pragma unroll
            for (int nt = 0; nt < 4; ++nt) {
                int n = wn + nt * 16 + l16;
                #pragma unroll
                for (int r = 0; r < 4; ++r) {
                    float v = fmaxf(acc[mt][nt][r] + b1v[nt], 0.f);
                    int m = mt * 16 + q * 4 + r;
                    s_a16[((n >> 3) * 64 + m) * 8 + (n & 7)] = f2bf(v);
                }
            }
    }

    // ---- GEMM2: C2[64][128] = h[64][256] @ w2 ; wave owns n in [wv*32, wv*32+32) ----
    const int wn2 = wv * 32;
    f32x4 acc2[4][2];
    #pragma unroll
    for (int a = 0; a < 4; ++a)
        #pragma unroll
        for (int b = 0; b < 2; ++b) acc2[a][b] = (f32x4){0.f, 0.f, 0.f, 0.f};

    for (int p = 0; p < 4; ++p) {
        __syncthreads();
        {
            const char* src = (const char*)(w2p) + p * 16384;
            #pragma unroll
            for (int it = 0; it < 4; ++it) {
                int chunk = it * 4 + wv;
                gl_lds16(src + chunk * 1024 + lane * 16, s_b + chunk * 1024);
            }
        }
        __syncthreads();
        #pragma unroll
        for (int ks = 0; ks < 2; ++ks) {
            int kcp = ks * 4 + q;
            short8 a[4], b[2];
            #pragma unroll
            for (int mt = 0; mt < 4; ++mt) a[mt] = s_a8[(p * 8 + kcp) * 64 + mt * 16 + l16];
            #pragma unroll
            for (int nt = 0; nt < 2; ++nt) b[nt] = s_b8[kcp * 128 + wn2 + nt * 16 + l16];
            #pragma unroll
            for (int mt = 0; mt < 4; ++mt)
                #pragma unroll
                for (int nt = 0; nt < 2; ++nt)
                    acc2[mt][nt] = __builtin_amdgcn_mfma_f32_16x16x32_bf16(a[mt], b[nt], acc2[mt][nt], 0, 0, 0);
        }
    }
    __syncthreads();

    {
        float b2v[2];
        #pragma unroll
        for (int nt = 0; nt < 2; ++nt) b2v[nt] = b2[wn2 + nt * 16 + l16];
        #pragma unroll
        for (int mt = 0; mt < 4; ++mt)
            #pragma unroll
            for (int nt = 0; nt < 2; ++nt)
                #pragma unroll
                for (int r = 0; r < 4; ++r)
                    s_cF[(mt * 16 + q * 4 + r) * 133 + wn2 + nt * 16 + l16] = acc2[mt][nt][r] + b2v[nt];
    }
    __syncthreads();

    // Stage mw1 pack while doing LN
    {
        const char* src = (const char*)(mw1p);
        #pragma unroll
        for (int it = 0; it < 4; ++it) {
            int chunk = it * 4 + wv;
            gl_lds16(src + chunk * 1024 + lane * 16, s_b + chunk * 1024);
        }
    }

    // ---- LayerNorm + write `updated` + proc A-frags ----
    {
        const int m = t >> 2, j = t & 3;
        float vloc[32];
        float sum = 0.f, sq = 0.f;
        #pragma unroll
        for (int i = 0; i < 32; ++i) {
            float v = s_cF[m * 133 + j * 32 + i];
            vloc[i] = v; sum += v; sq += v * v;
        }
        sum += __shfl_xor(sum, 1, 4); sq += __shfl_xor(sq, 1, 4);
        sum += __shfl_xor(sum, 2, 4); sq += __shfl_xor(sq, 2, 4);
        float mu = sum * (1.f / 128.f);
        float rs = rsqrtf(sq * (1.f / 128.f) - mu * mu + 1e-5f);
        const bool wvalid = (m < nvalid);
        const int node = nodes3[m];
        float4* outp = (float4*)&out[(size_t)node * FD + j * 32];
        const float4* g4 = (const float4*)&ln_g[j * 32];
        const float4* bb4 = (const float4*)&ln_b[j * 32];
        #pragma unroll
        for (int i8 = 0; i8 < 4; ++i8) {
            unsigned short pk[8];
            #pragma unroll
            for (int h = 0; h < 2; ++h) {
                float4 g = g4[i8 * 2 + h], bb = bb4[i8 * 2 + h];
                float4 o;
                o.x = (vloc[i8 * 8 + h * 4 + 0] - mu) * rs * g.x + bb.x;
                o.y = (vloc[i8 * 8 + h * 4 + 1] - mu) * rs * g.y + bb.y;
                o.z = (vloc[i8 * 8 + h * 4 + 2] - mu) * rs * g.z + bb.z;
                o.w = (vloc[i8 * 8 + h * 4 + 3] - mu) * rs * g.w + bb.w;
                if (wvalid) outp[i8 * 2 + h] = o;
                pk[h * 4 + 0] = f2bf(o.x); pk[h * 4 + 1] = f2bf(o.y);
                pk[h * 4 + 2] = f2bf(o.z); pk[h * 4 + 3] = f2bf(o.w);
            }
            int kc = j * 4 + i8;
            *(short8*)&s_a16[PF_BYTE / 2 + (kc * 64 + m) * 8] = *(short8*)pk;
        }
    }
    __syncthreads();

    // ---- Murray head ----
    {
        const int wn3 = wv * 16;
        f32x4 acc3[4];
        #pragma unroll
        for (int a = 0; a < 4; ++a) acc3[a] = (f32x4){0.f, 0.f, 0.f, 0.f};
        #pragma unroll
        for (int ks = 0; ks < 4; ++ks) {
            int kcq = ks * 4 + q;
            short8 b = s_b8[kcq * 64 + wn3 + l16];
            #pragma unroll
            for (int mt = 0; mt < 4; ++mt) {
                short8 a = s_a8[PF_BYTE / 16 + kcq * 64 + mt * 16 + l16];
                acc3[mt] = __builtin_amdgcn_mfma_f32_16x16x32_bf16(a, b, acc3[mt], 0, 0, 0);
            }
        }
        float mb1v = mb1[wn3 + l16];
        float mw2v = mw2[wn3 + l16];
        float part[16];
        #pragma unroll
        for (int mt = 0; mt < 4; ++mt)
            #pragma unroll
            for (int r = 0; r < 4; ++r) {
                float v = fmaxf(acc3[mt][r] + mb1v, 0.f) * mw2v;
                #pragma unroll
                for (int d = 1; d < 16; d <<= 1) v += __shfl_xor(v, d, 16);
                part[mt * 4 + r] = v;
            }
        if (l16 == 0) {
            #pragma unroll
            for (int mt = 0; mt < 4; ++mt)
                #pragma unroll
                for (int r = 0; r < 4; ++r)
                    red[wv * 64 + mt * 16 + q * 4 + r] = part[mt * 4 + r];
        }
    }
    __syncthreads();
    if (t < 64 && t < nvalid) {
        float v = red[t] + red[64 + t] + red[128 + t] + red[192 + t] + mb2[0];
        out[(size_t)NN * FD + nodes3[t]] = 1.f / (1.f + expf(-v));
    }
}

extern "C" void kernel_launch(void* const* d_in, const int* in_sizes, int n_in,
                              void* d_out, int out_size, void* d_ws, size_t ws_size,
                              hipStream_t stream) {
    const float* x   = (const float*)d_in[0];
    const int*   ei  = (const int*)d_in[1];
    const int* types = (const int*)d_in[2];
    const float* w1  = (const float*)d_in[3];
    const float* b1  = (const float*)d_in[4];
    const float* w2  = (const float*)d_in[5];
    const float* b2  = (const float*)d_in[6];
    const float* lg  = (const float*)d_in[7];
    const float* lb  = (const float*)d_in[8];
    const float* mw1 = (const float*)d_in[9];
    const float* mb1 = (const float*)d_in[10];
    const float* mw2 = (const float*)d_in[11];
    const float* mb2 = (const float*)d_in[12];
    float* out = (float*)d_out;
    int* ws = (int*)d_ws;

    unsigned short* w1p  = (unsigned short*)((char*)d_ws + WS_PACK_BYTES);
    unsigned short* w2p  = w1p + W1P_ELEMS;
    unsigned short* mw1p = w2p + W2P_ELEMS;

    k_init_pack<<<(NN + 255) / 256, 256, 0, stream>>>(w1, w2, mw1, w1p, w2p, mw1p, ws);
    k_min1<<<(NE + 255) / 256, 256, 0, stream>>>(ei, ws);
    k_min2<<<(NE + 255) / 256, 256, 0, stream>>>(ei, ws);
    k_copy_compact<<<(NN * FD / 4) / 256, 256, 0, stream>>>((const float4*)x, (float4*)out, types, ws);
    k_mlp<<<(NN + 63) / 64, 256, 0, stream>>>(x, b1, b2, lg, lb, mb1, mw2, mb2,
                                              w1p, w2p, mw1p, ws, out);
}